// Round 11
// baseline (283.989 us; speedup 1.0000x reference)
//
#include <hip/hip_runtime.h>

// Problem constants (fixed by the reference file)
constexpr int C_  = 128;
constexpr int D_  = 32;
constexpr int H_  = 64;
constexpr int W_  = 64;
constexpr int PD = 4;
constexpr int PH = 7;
constexpr int PW = 7;
constexpr int SR = 2;          // sampling ratio
constexpr float SCALE = 0.25f; // spatial scale
constexpr int S_ = D_ * H_ * W_;           // 131072 spatial elements
constexpr int BINS_PER_ROI = PD * PH * PW; // 196
constexpr int SLAB = PH * PW;              // 49 bins per (roi, pd) slab

typedef float vf4 __attribute__((ext_vector_type(4)));  // native vec for NT builtins
typedef float f32x2 __attribute__((ext_vector_type(2))); // for v_pk_fma_f32

// ---------------------------------------------------------------------------
// Per-axis sampling (matches reference _axis + sample_coords exactly)
// ---------------------------------------------------------------------------
__device__ __forceinline__ void axis2(float start, float extent, int P, int p,
                                      int size, int lo[2], int hi[2],
                                      float w[2], bool v[2]) {
    float bin = extent / (float)P;
#pragma unroll
    for (int u = 0; u < 2; ++u) {
        float t = ((float)(p * SR + u) + 0.5f) / (float)SR;
        float coord = start + t * bin;
        v[u] = (coord >= -1.0f) && (coord <= (float)size);
        float cc = fminf(fmaxf(coord, 0.0f), (float)size - 1.0f);
        float fl = floorf(cc);
        lo[u] = (int)fl;
        hi[u] = min(lo[u] + 1, size - 1);
        w[u] = cc - fl;
    }
}

// ---------------------------------------------------------------------------
// Merged-axis weights (validated: absmax 0.0078): for SR=2 the two subsamples
// in a bin touch at most 4 consecutive voxels. Per-axis validity folds into
// the weights; weights >= 0 and are EXACTLY +0.0 for untouched voxels, so a
// bit-test w==0 is an exact skip criterion. Nonzero weights always map to
// in-range voxel indices (clamped lo/hi).
// bin (= extent/P) is passed in precomputed so per-bin calls avoid the
// divide; the division itself is hoisted once per wave (identical float op).
// ---------------------------------------------------------------------------
struct AxisW {
    int base;
    float w[4];
};

__device__ __forceinline__ AxisW axis_merge_bin(float start, float bin, int p,
                                                int size) {
    // u = 0
    const float t0 = ((float)(p * SR) + 0.5f) / (float)SR;
    const float c0 = start + t0 * bin;
    const float va = (c0 >= -1.0f && c0 <= (float)size) ? 1.0f : 0.0f;
    const float cc0 = fminf(fmaxf(c0, 0.0f), (float)size - 1.0f);
    const float fl0 = floorf(cc0);
    const int lo0 = (int)fl0;
    const int hi0 = min(lo0 + 1, size - 1);
    const float f0 = cc0 - fl0;
    const float a0 = (1.0f - f0) * va;
    const float a1 = f0 * va;
    // u = 1
    const float t1 = ((float)(p * SR + 1) + 0.5f) / (float)SR;
    const float c1 = start + t1 * bin;
    const float vb = (c1 >= -1.0f && c1 <= (float)size) ? 1.0f : 0.0f;
    const float cc1 = fminf(fmaxf(c1, 0.0f), (float)size - 1.0f);
    const float fl1 = floorf(cc1);
    const int lo1 = (int)fl1;
    const int hi1 = min(lo1 + 1, size - 1);
    const float f1 = cc1 - fl1;
    const float b0 = (1.0f - f1) * vb;
    const float b1 = f1 * vb;

    const int dh0 = hi0 - lo0; // 0..1
    const int dl1 = lo1 - lo0; // 0..2 (step < 2 voxels)
    const int dh1 = hi1 - lo0; // 0..3

    float w0 = a0, w1 = 0.f, w2 = 0.f, w3 = 0.f;
    if (dh0 == 0) w0 += a1; else w1 += a1;
    w0 += (dl1 == 0) ? b0 : 0.f;
    w1 += (dl1 == 1) ? b0 : 0.f;
    w2 += (dl1 == 2) ? b0 : 0.f;
    w0 += (dh1 == 0) ? b1 : 0.f;
    w1 += (dh1 == 1) ? b1 : 0.f;
    w2 += (dh1 == 2) ? b1 : 0.f;
    w3 += (dh1 == 3) ? b1 : 0.f;

    AxisW r;
    r.base = lo0;
    r.w[0] = w0; r.w[1] = w1; r.w[2] = w2; r.w[3] = w3;
    return r;
}

__device__ __forceinline__ AxisW axis_merge(float start, float extent, int P,
                                            int p, int size) {
    return axis_merge_bin(start, extent / (float)P, p, size);
}

// float -> bf16 bits (round-to-nearest-even; inputs are finite)
__device__ __forceinline__ unsigned int f2bf(float f) {
    unsigned int u = __float_as_uint(f);
    u += 0x7fffu + ((u >> 16) & 1u);
    return u >> 16;
}

// ---------------------------------------------------------------------------
// Transpose + cast: [N, C, S] f32 -> [N, S, C] bf16.
// 256-s x 128-c tile per block; XOR-swizzled LDS. Also zeroes a 1 KB pad
// right after the bf16 features: the slab kernel's x-row loads can overrun
// the array end by <= 768 B with weight exactly 0 -- the pad must be finite
// (not workspace poison) so 0 * pad == 0.
// ---------------------------------------------------------------------------
__global__ __launch_bounds__(512) void transpose_bf16(
    const float* __restrict__ in, unsigned int* __restrict__ outp) {
    __shared__ unsigned int tileu[256][64]; // [s][swizzled cpair], 64 KB
    const int n  = blockIdx.y;
    const int s0 = blockIdx.x * 256;
    const int t  = threadIdx.x;

    const float* src = in + (size_t)n * C_ * S_;
    unsigned int* dst = outp + (size_t)n * (C_ / 2) * S_;

    if (n == 0 && blockIdx.x == 0 && t < 256) {
        // zero the 1 KB pad after all features (N = gridDim.y batches)
        outp[(size_t)gridDim.y * (C_ / 2) * S_ + t] = 0u;
    }

    // Load phase: 1 KB contiguous per channel row per wave instruction.
    {
        const int sl  = t & 63;  // s quad index 0..63 -> s = 4*sl+q
        const int cp0 = t >> 6;  // 0..7
#pragma unroll
        for (int p = 0; p < 8; ++p) {
            const int cp = cp0 + 8 * p; // channel pair 0..63
            const int c = cp * 2;
            const vf4 a = __builtin_nontemporal_load(
                (const vf4*)&src[(size_t)c * S_ + (s0 + 4 * sl)]);
            const vf4 b = __builtin_nontemporal_load(
                (const vf4*)&src[(size_t)(c + 1) * S_ + (s0 + 4 * sl)]);
            const int col = cp ^ (sl & 31); // (s>>2) == sl for q in 0..3
            tileu[4 * sl + 0][col] = f2bf(a.x) | (f2bf(b.x) << 16);
            tileu[4 * sl + 1][col] = f2bf(a.y) | (f2bf(b.y) << 16);
            tileu[4 * sl + 2][col] = f2bf(a.z) | (f2bf(b.z) << 16);
            tileu[4 * sl + 3][col] = f2bf(a.w) | (f2bf(b.w) << 16);
        }
    }
    __syncthreads();
    // Store phase: 512 B contiguous per wave (2 rows x 256 B).
    {
        const int cp2   = (t & 31) * 2; // even logical col 0..62
        const int rbase = t >> 5;       // 0..15
#pragma unroll
        for (int it = 0; it < 16; ++it) {
            const int s = rbase + 16 * it;
            const int w = (s >> 2) & 31;
            uint2 v;
            v.x = tileu[s][cp2 ^ w];
            v.y = tileu[s][(cp2 + 1) ^ w];
            *(uint2*)&dst[(size_t)(s0 + s) * (C_ / 2) + cp2] = v;
        }
    }
}

// ---------------------------------------------------------------------------
// Main kernel, Round-11: wave-per-pw-COLUMN (7 bins per wave).
//   Ledger: VALU/2 null (R5), bytes*0.6 null (R6), occupancy*1.75 null/+2
//   (R10), thin waves -9us (R8). R8's regression fingered per-wave serial
//   SETUP (roi load -> divide chains -> addresses). This round amortizes it:
//   block = one (roi,pd) slab, 7 waves; wave w owns the pw=w column of 7
//   bins (slots ph*7+w). ROI decode, z-merge, x-merge, per-lane x-weight and
//   z-row offsets are computed ONCE per wave; only the y-merge (divide
//   hoisted: biny = rh/7 once) repeats per bin. Wave count drops 7x
//   (50k -> 7k) at unchanged 7 waves/SIMD (72-VGPR cap, 25.9 KB LDS,
//   4 blocks/CU). Inner per-bin gather/FMA is R10's two-batch q[8] verbatim
//   (scalar zero-row skip at load and compute; sched_barrier keeps batch-1
//   loads from inflating live registers).
//   Nonzero rows always in-range z/y; x overrun (<=768 B) lands in the
//   zeroed pad; pad*0 == 0. Cross-voxel reduce: shfl_xor 16/32; slab staged
//   in LDS and stored as 49-dword-contiguous runs per channel.
//   XCD swizzle (R%8==0): all 4 slabs of one ROI share blockIdx&7.
// ---------------------------------------------------------------------------
__global__ __launch_bounds__(448, 7) void roi_align_slab7(
    const unsigned short* __restrict__ ft, // [N, D, H, W, C] bf16
    const float* __restrict__ rois,        // [R, 7]
    float* __restrict__ out,               // [R, C, PD, PH, PW]
    int R) {
    __shared__ float tile[SLAB][132]; // 25.9 KB

    int roi, pd;
    {
        const int B = blockIdx.x;
        if ((R & 7) == 0) {
            const int xcd = B & 7;
            const int j = B >> 3;
            roi = xcd + 8 * (j >> 2);
            pd = j & 3;
        } else {
            roi = B >> 2;
            pd = B & 3;
        }
    }

    const int t = threadIdx.x;
    const int w = t >> 6;     // wave 0..6 == pw
    const int lane = t & 63;

    const float* roip = rois + (size_t)roi * 7;
    const int b = (int)roip[0];
    const float x1 = roip[1] * SCALE, y1 = roip[2] * SCALE, z1 = roip[3] * SCALE;
    const float x2 = roip[4] * SCALE, y2 = roip[5] * SCALE, z2 = roip[6] * SCALE;
    const float rd = fmaxf(z2 - z1, 1.0f);
    const float rh = fmaxf(y2 - y1, 1.0f);
    const float rw = fmaxf(x2 - x1, 1.0f);

    // ---- per-wave setup (once, amortized over 7 bins) ----
    AxisW az = axis_merge(z1, rd, PD, pd, D_);
    {
        const float s = 1.0f / (SR * SR * SR); // fold sample mean into z
        az.w[0] *= s; az.w[1] *= s; az.w[2] *= s; az.w[3] *= s;
    }
    const AxisW ax = axis_merge(x1, rw, PW, w, W_); // pw = w, fixed per wave
    const float biny = rh / (float)PH;              // y divide hoisted

    int zw[4];
#pragma unroll
    for (int i = 0; i < 4; ++i)
        zw[i] = __builtin_amdgcn_readfirstlane((int)__float_as_uint(az.w[i]));

    // per-lane x-voxel weight (cndmask tree)
    const int v = lane >> 4;
    float wxl = ax.w[0];
    wxl = (v == 1) ? ax.w[1] : wxl;
    wxl = (v == 2) ? ax.w[2] : wxl;
    wxl = (v == 3) ? ax.w[3] : wxl;

    unsigned zrow[4];
#pragma unroll
    for (int iz = 0; iz < 4; ++iz) {
        const int zz = min(az.base + iz, D_ - 1);
        zrow[iz] = (((unsigned)b * D_ + (unsigned)zz) * H_) *
                   (unsigned)(W_ * C_);
    }

    const unsigned short* lanep = ft + (unsigned)lane * 8; // +16 B per lane

    // ---- per-bin loop: ph = 0..6 ----
#pragma unroll
    for (int ph = 0; ph < PH; ++ph) {
        const AxisW ay = axis_merge_bin(y1, biny, ph, H_);
        int yw[4];
#pragma unroll
        for (int i = 0; i < 4; ++i)
            yw[i] = __builtin_amdgcn_readfirstlane(
                (int)__float_as_uint(ay.w[i]));
        unsigned yoff[4];
#pragma unroll
        for (int iy = 0; iy < 4; ++iy) {
            const int yy = min(ay.base + iy, H_ - 1);
            yoff[iy] = ((unsigned)yy * W_ + (unsigned)ax.base) * C_;
        }

        f32x2 acc2[4];
#pragma unroll
        for (int j = 0; j < 4; ++j) { acc2[j].x = 0.f; acc2[j].y = 0.f; }

        uint4 q[8];
#pragma unroll
        for (int zb = 0; zb < 2; ++zb) {
            if (zb == 1) __builtin_amdgcn_sched_barrier(0); // cap live regs
            // loads for z-planes {2zb, 2zb+1}, scalar-skipped
#pragma unroll
            for (int dz = 0; dz < 2; ++dz) {
                const int iz = 2 * zb + dz;
                if (zw[iz] == 0) continue;
#pragma unroll
                for (int iy = 0; iy < 4; ++iy) {
                    if (yw[iy] == 0) continue;
                    q[dz * 4 + iy] =
                        *(const uint4*)(lanep + zrow[iz] + yoff[iy]);
                }
            }
            // packed FMA over the same nonzero rows
#pragma unroll
            for (int dz = 0; dz < 2; ++dz) {
                const int iz = 2 * zb + dz;
                if (zw[iz] == 0) continue;
#pragma unroll
                for (int iy = 0; iy < 4; ++iy) {
                    if (yw[iy] == 0) continue;
                    const float wf = (az.w[iz] * ay.w[iy]) * wxl;
                    f32x2 wf2; wf2.x = wf; wf2.y = wf;
                    const uint4 qq = q[dz * 4 + iy];
                    f32x2 p;
                    p.x = __uint_as_float(qq.x << 16);
                    p.y = __uint_as_float(qq.x & 0xffff0000u);
                    acc2[0] = __builtin_elementwise_fma(p, wf2, acc2[0]);
                    p.x = __uint_as_float(qq.y << 16);
                    p.y = __uint_as_float(qq.y & 0xffff0000u);
                    acc2[1] = __builtin_elementwise_fma(p, wf2, acc2[1]);
                    p.x = __uint_as_float(qq.z << 16);
                    p.y = __uint_as_float(qq.z & 0xffff0000u);
                    acc2[2] = __builtin_elementwise_fma(p, wf2, acc2[2]);
                    p.x = __uint_as_float(qq.w << 16);
                    p.y = __uint_as_float(qq.w & 0xffff0000u);
                    acc2[3] = __builtin_elementwise_fma(p, wf2, acc2[3]);
                }
            }
        }

        // reduce over the 4 x-voxel partitions (lanes ^16, ^32), stage in LDS
        const int slot = ph * PW + w;
#pragma unroll
        for (int j = 0; j < 4; ++j) {
            float sx = acc2[j].x;
            sx += __shfl_xor(sx, 16);
            sx += __shfl_xor(sx, 32);
            float sy = acc2[j].y;
            sy += __shfl_xor(sy, 16);
            sy += __shfl_xor(sy, 32);
            if (lane < 16) {
                tile[slot][lane * 8 + 2 * j]     = sx;
                tile[slot][lane * 8 + 2 * j + 1] = sy;
            }
        }
    }

    __syncthreads();

    // Store the whole slab: out[roi][c][pd*49 + o], 49-dword runs per channel.
    const size_t obase = (size_t)roi * C_ * BINS_PER_ROI + (size_t)pd * SLAB;
#pragma unroll
    for (int it = 0; it < 14; ++it) {
        const int idx = t + it * 448; // 0..6271 = 128 ch * 49 slots
        const int c = idx / SLAB;
        const int o = idx - c * SLAB;
        __builtin_nontemporal_store(tile[o][c],
                                    &out[obase + (size_t)c * BINS_PER_ROI + o]);
    }
}

// ---------------------------------------------------------------------------
// Fallback: thread-per-output, native layout (tiny ws only).
// ---------------------------------------------------------------------------
__global__ void roi_align_direct(const float* __restrict__ feat,
                                 const float* __restrict__ rois,
                                 float* __restrict__ out, int total) {
    const int tid = blockIdx.x * blockDim.x + threadIdx.x;
    if (tid >= total) return;
    int t = tid;
    const int pw = t % PW; t /= PW;
    const int ph = t % PH; t /= PH;
    const int pd = t % PD; t /= PD;
    const int c = t % C_;  t /= C_;
    const int r = t;

    const float* roi = rois + (size_t)r * 7;
    const int b = (int)roi[0];
    const float x1 = roi[1] * SCALE, y1 = roi[2] * SCALE, z1 = roi[3] * SCALE;
    const float x2 = roi[4] * SCALE, y2 = roi[5] * SCALE, z2 = roi[6] * SCALE;
    const float rd = fmaxf(z2 - z1, 1.0f);
    const float rh = fmaxf(y2 - y1, 1.0f);
    const float rw = fmaxf(x2 - x1, 1.0f);

    int zlo[2], zhi[2], ylo[2], yhi[2], xlo[2], xhi[2];
    float wz[2], wy[2], wx[2];
    bool vz[2], vy[2], vx[2];
    axis2(z1, rd, PD, pd, D_, zlo, zhi, wz, vz);
    axis2(y1, rh, PH, ph, H_, ylo, yhi, wy, vy);
    axis2(x1, rw, PW, pw, W_, xlo, xhi, wx, vx);

    const float* fc = feat + ((size_t)b * C_ + c) * S_;
    float acc = 0.0f;
#pragma unroll
    for (int i = 0; i < 2; ++i) {
        if (!vz[i]) continue;
#pragma unroll
        for (int j = 0; j < 2; ++j) {
            if (!vy[j]) continue;
            const size_t r00 = ((size_t)zlo[i] * H_ + ylo[j]) * W_;
            const size_t r10 = ((size_t)zhi[i] * H_ + ylo[j]) * W_;
            const size_t r01 = ((size_t)zlo[i] * H_ + yhi[j]) * W_;
            const size_t r11 = ((size_t)zhi[i] * H_ + yhi[j]) * W_;
            const float wz1 = wz[i], wz0 = 1.0f - wz1;
            const float wy1 = wy[j], wy0 = 1.0f - wy1;
#pragma unroll
            for (int k = 0; k < 2; ++k) {
                if (!vx[k]) continue;
                const float wx1 = wx[k], wx0 = 1.0f - wx1;
                acc += wz0 * (wy0 * (wx0 * fc[r00 + xlo[k]] + wx1 * fc[r00 + xhi[k]]) +
                              wy1 * (wx0 * fc[r01 + xlo[k]] + wx1 * fc[r01 + xhi[k]])) +
                       wz1 * (wy0 * (wx0 * fc[r10 + xlo[k]] + wx1 * fc[r10 + xhi[k]]) +
                              wy1 * (wx0 * fc[r11 + xlo[k]] + wx1 * fc[r11 + xhi[k]]));
            }
        }
    }
    out[tid] = acc * (1.0f / (SR * SR * SR));
}

extern "C" void kernel_launch(void* const* d_in, const int* in_sizes, int n_in,
                              void* d_out, int out_size, void* d_ws,
                              size_t ws_size, hipStream_t stream) {
    const float* features = (const float*)d_in[0];
    const float* rois = (const float*)d_in[1];
    float* out = (float*)d_out;

    const int R = in_sizes[1] / 7;
    const int N = in_sizes[0] / (C_ * S_);
    const size_t need = (size_t)in_sizes[0] * sizeof(unsigned short) + 1024;

    if (ws_size >= need) {
        unsigned short* ft = (unsigned short*)d_ws; // [N, D, H, W, C] bf16

        dim3 tg(S_ / 256, N);
        transpose_bf16<<<tg, 512, 0, stream>>>(features, (unsigned int*)ft);

        roi_align_slab7<<<R * PD, 448, 0, stream>>>(ft, rois, out, R);
    } else {
        const int total = R * C_ * BINS_PER_ROI;
        roi_align_direct<<<(total + 255) / 256, 256, 0, stream>>>(
            features, rois, out, total);
    }
}

// Round 12
// 250.910 us; speedup vs baseline: 1.1318x; 1.1318x over previous
//
#include <hip/hip_runtime.h>

// Problem constants (fixed by the reference file)
constexpr int C_  = 128;
constexpr int D_  = 32;
constexpr int H_  = 64;
constexpr int W_  = 64;
constexpr int PD = 4;
constexpr int PH = 7;
constexpr int PW = 7;
constexpr int SR = 2;          // sampling ratio
constexpr float SCALE = 0.25f; // spatial scale
constexpr int S_ = D_ * H_ * W_;           // 131072 spatial elements
constexpr int BINS_PER_ROI = PD * PH * PW; // 196
constexpr int SLAB = PH * PW;              // 49 bins per (roi, pd) slab

typedef float vf4 __attribute__((ext_vector_type(4)));  // native vec for NT builtins
typedef float f32x2 __attribute__((ext_vector_type(2))); // for v_pk_fma_f32

// ---------------------------------------------------------------------------
// Per-axis sampling (matches reference _axis + sample_coords exactly)
// ---------------------------------------------------------------------------
__device__ __forceinline__ void axis2(float start, float extent, int P, int p,
                                      int size, int lo[2], int hi[2],
                                      float w[2], bool v[2]) {
    float bin = extent / (float)P;
#pragma unroll
    for (int u = 0; u < 2; ++u) {
        float t = ((float)(p * SR + u) + 0.5f) / (float)SR;
        float coord = start + t * bin;
        v[u] = (coord >= -1.0f) && (coord <= (float)size);
        float cc = fminf(fmaxf(coord, 0.0f), (float)size - 1.0f);
        float fl = floorf(cc);
        lo[u] = (int)fl;
        hi[u] = min(lo[u] + 1, size - 1);
        w[u] = cc - fl;
    }
}

// ---------------------------------------------------------------------------
// Merged-axis weights (validated: absmax 0.0078): for SR=2 the two subsamples
// in a bin touch at most 4 consecutive voxels. Per-axis validity folds into
// the weights; weights >= 0 and are EXACTLY +0.0 for untouched voxels, so a
// bit-test w==0 is an exact skip criterion. Nonzero weights always map to
// in-range voxel indices (clamped lo/hi).
// ---------------------------------------------------------------------------
struct AxisW {
    int base;
    float w[4];
};

__device__ __forceinline__ AxisW axis_merge(float start, float extent, int P,
                                            int p, int size) {
    const float bin = extent / (float)P;
    // u = 0
    const float t0 = ((float)(p * SR) + 0.5f) / (float)SR;
    const float c0 = start + t0 * bin;
    const float va = (c0 >= -1.0f && c0 <= (float)size) ? 1.0f : 0.0f;
    const float cc0 = fminf(fmaxf(c0, 0.0f), (float)size - 1.0f);
    const float fl0 = floorf(cc0);
    const int lo0 = (int)fl0;
    const int hi0 = min(lo0 + 1, size - 1);
    const float f0 = cc0 - fl0;
    const float a0 = (1.0f - f0) * va;
    const float a1 = f0 * va;
    // u = 1
    const float t1 = ((float)(p * SR + 1) + 0.5f) / (float)SR;
    const float c1 = start + t1 * bin;
    const float vb = (c1 >= -1.0f && c1 <= (float)size) ? 1.0f : 0.0f;
    const float cc1 = fminf(fmaxf(c1, 0.0f), (float)size - 1.0f);
    const float fl1 = floorf(cc1);
    const int lo1 = (int)fl1;
    const int hi1 = min(lo1 + 1, size - 1);
    const float f1 = cc1 - fl1;
    const float b0 = (1.0f - f1) * vb;
    const float b1 = f1 * vb;

    const int dh0 = hi0 - lo0; // 0..1
    const int dl1 = lo1 - lo0; // 0..2 (step < 2 voxels)
    const int dh1 = hi1 - lo0; // 0..3

    float w0 = a0, w1 = 0.f, w2 = 0.f, w3 = 0.f;
    if (dh0 == 0) w0 += a1; else w1 += a1;
    w0 += (dl1 == 0) ? b0 : 0.f;
    w1 += (dl1 == 1) ? b0 : 0.f;
    w2 += (dl1 == 2) ? b0 : 0.f;
    w0 += (dh1 == 0) ? b1 : 0.f;
    w1 += (dh1 == 1) ? b1 : 0.f;
    w2 += (dh1 == 2) ? b1 : 0.f;
    w3 += (dh1 == 3) ? b1 : 0.f;

    AxisW r;
    r.base = lo0;
    r.w[0] = w0; r.w[1] = w1; r.w[2] = w2; r.w[3] = w3;
    return r;
}

// float -> bf16 bits (round-to-nearest-even; inputs are finite)
__device__ __forceinline__ unsigned int f2bf(float f) {
    unsigned int u = __float_as_uint(f);
    u += 0x7fffu + ((u >> 16) & 1u);
    return u >> 16;
}

// ---------------------------------------------------------------------------
// Transpose + cast: [N, C, S] f32 -> [N, S, C] bf16.
// 256-s x 128-c tile per block; XOR-swizzled LDS. Also zeroes a 1 KB pad
// right after the bf16 features: the slab kernel's x-row loads can overrun
// the array end by <= 768 B with weight exactly 0 -- the pad must be finite
// (not workspace poison) so 0 * pad == 0.
// ---------------------------------------------------------------------------
__global__ __launch_bounds__(512) void transpose_bf16(
    const float* __restrict__ in, unsigned int* __restrict__ outp) {
    __shared__ unsigned int tileu[256][64]; // [s][swizzled cpair], 64 KB
    const int n  = blockIdx.y;
    const int s0 = blockIdx.x * 256;
    const int t  = threadIdx.x;

    const float* src = in + (size_t)n * C_ * S_;
    unsigned int* dst = outp + (size_t)n * (C_ / 2) * S_;

    if (n == 0 && blockIdx.x == 0 && t < 256) {
        // zero the 1 KB pad after all features (N = gridDim.y batches)
        outp[(size_t)gridDim.y * (C_ / 2) * S_ + t] = 0u;
    }

    // Load phase: 1 KB contiguous per channel row per wave instruction.
    {
        const int sl  = t & 63;  // s quad index 0..63 -> s = 4*sl+q
        const int cp0 = t >> 6;  // 0..7
#pragma unroll
        for (int p = 0; p < 8; ++p) {
            const int cp = cp0 + 8 * p; // channel pair 0..63
            const int c = cp * 2;
            const vf4 a = __builtin_nontemporal_load(
                (const vf4*)&src[(size_t)c * S_ + (s0 + 4 * sl)]);
            const vf4 b = __builtin_nontemporal_load(
                (const vf4*)&src[(size_t)(c + 1) * S_ + (s0 + 4 * sl)]);
            const int col = cp ^ (sl & 31); // (s>>2) == sl for q in 0..3
            tileu[4 * sl + 0][col] = f2bf(a.x) | (f2bf(b.x) << 16);
            tileu[4 * sl + 1][col] = f2bf(a.y) | (f2bf(b.y) << 16);
            tileu[4 * sl + 2][col] = f2bf(a.z) | (f2bf(b.z) << 16);
            tileu[4 * sl + 3][col] = f2bf(a.w) | (f2bf(b.w) << 16);
        }
    }
    __syncthreads();
    // Store phase: 512 B contiguous per wave (2 rows x 256 B).
    {
        const int cp2   = (t & 31) * 2; // even logical col 0..62
        const int rbase = t >> 5;       // 0..15
#pragma unroll
        for (int it = 0; it < 16; ++it) {
            const int s = rbase + 16 * it;
            const int w = (s >> 2) & 31;
            uint2 v;
            v.x = tileu[s][cp2 ^ w];
            v.y = tileu[s][(cp2 + 1) ^ w];
            *(uint2*)&dst[(size_t)(s0 + s) * (C_ / 2) + cp2] = v;
        }
    }
}

// ---------------------------------------------------------------------------
// Main kernel, wave-per-slot (FINAL = Round-10 best, 251.2 us):
//   R11's 7-bins-per-wave amortization collapsed chip-wide MLP (7k waves x
//   8 loads vs 50k x 8-16) and regressed 30 us -> reverted. This structure
//   maximizes concurrent scattered-row requests, which the ledger (R5 VALU
//   null, R6 bytes null, R8 thin-wave -9us, R10 +2us, R11 -30us) shows is
//   the binding resource.
//
//   grid = R * PD * 7 blocks of 448 threads = 7 waves; wave w handles bin
//   slot = part*7 + w. Wave-uniform control flow; zero-weight rows skipped
//   at load AND compute by scalar branches (exact +0 bit test). Lane l:
//   x-voxel l>>4, channels (l&15)*8..+7 (dwordx4, 1 KB per wave-row).
//   Two-batch q[8] gather under __launch_bounds__(448,7) (72-VGPR cap,
//   7 waves/SIMD); sched_barrier stops batch-1 loads from inflating live
//   registers. Nonzero rows always in-range z/y; x overrun (<=768 B) lands
//   in the zeroed pad; pad*0 == 0. Cross-voxel reduce: shfl_xor 16/32.
//   XCD swizzle (R%8==0): all 28 blocks of one ROI share blockIdx&7.
// ---------------------------------------------------------------------------
__global__ __launch_bounds__(448, 7) void roi_align_slot(
    const unsigned short* __restrict__ ft, // [N, D, H, W, C] bf16
    const float* __restrict__ rois,        // [R, 7]
    float* __restrict__ out,               // [R, C, PD, PH, PW]
    int R) {
    __shared__ float tile[7][128]; // [slot-in-part][channel]

    int roi, pd, part;
    {
        const int B = blockIdx.x;
        if ((R & 7) == 0) {
            const int xcd = B & 7;
            const int j = B >> 3;
            roi = xcd + 8 * (j / 28);
            const int sub = j % 28;
            pd = sub / 7;
            part = sub - pd * 7;
        } else {
            roi = B / 28;
            const int sub = B - roi * 28;
            pd = sub / 7;
            part = sub - pd * 7;
        }
    }

    const int t = threadIdx.x;
    const int w = t >> 6;     // wave 0..6
    const int lane = t & 63;
    const int slot = part * 7 + w; // 0..48, always valid

    const float* roip = rois + (size_t)roi * 7;
    const int b = (int)roip[0];
    const float x1 = roip[1] * SCALE, y1 = roip[2] * SCALE, z1 = roip[3] * SCALE;
    const float x2 = roip[4] * SCALE, y2 = roip[5] * SCALE, z2 = roip[6] * SCALE;
    const float rd = fmaxf(z2 - z1, 1.0f);
    const float rh = fmaxf(y2 - y1, 1.0f);
    const float rw = fmaxf(x2 - x1, 1.0f);

    // z-axis merged weights (uniform for the slab); fold in 1/SR^3.
    // 0 * (1/8) == +0, so the bit-test skip stays exact.
    AxisW az = axis_merge(z1, rd, PD, pd, D_);
    {
        const float s = 1.0f / (SR * SR * SR);
        az.w[0] *= s; az.w[1] *= s; az.w[2] *= s; az.w[3] *= s;
    }

    const int ph = slot / PW;
    const int pw = slot - ph * PW;
    const AxisW ay = axis_merge(y1, rh, PH, ph, H_);
    const AxisW ax = axis_merge(x1, rw, PW, pw, W_);

    // wave-uniform row-skip predicates (weight bits; exact +0 test)
    int zw[4], yw[4];
#pragma unroll
    for (int i = 0; i < 4; ++i) {
        zw[i] = __builtin_amdgcn_readfirstlane((int)__float_as_uint(az.w[i]));
        yw[i] = __builtin_amdgcn_readfirstlane((int)__float_as_uint(ay.w[i]));
    }

    // per-lane x-voxel weight (cndmask tree, no runtime array indexing)
    const int v = lane >> 4;
    float wxl = ax.w[0];
    wxl = (v == 1) ? ax.w[1] : wxl;
    wxl = (v == 2) ? ax.w[2] : wxl;
    wxl = (v == 3) ? ax.w[3] : wxl;

    // y-row element offsets (shared by both z-batches)
    unsigned yoff[4];
#pragma unroll
    for (int iy = 0; iy < 4; ++iy) {
        const int yy = min(ay.base + iy, H_ - 1);
        yoff[iy] = ((unsigned)yy * W_ + (unsigned)ax.base) * C_;
    }
    unsigned zrow[4];
#pragma unroll
    for (int iz = 0; iz < 4; ++iz) {
        const int zz = min(az.base + iz, D_ - 1);
        zrow[iz] = (((unsigned)b * D_ + (unsigned)zz) * H_) *
                   (unsigned)(W_ * C_);
    }

    const unsigned short* lanep = ft + (unsigned)lane * 8; // +16 B per lane

    f32x2 acc2[4];
#pragma unroll
    for (int j = 0; j < 4; ++j) { acc2[j].x = 0.f; acc2[j].y = 0.f; }

    // Two serialized batches over z-plane pairs; q[8] reused (32 VGPR staged).
    uint4 q[8];
#pragma unroll
    for (int zb = 0; zb < 2; ++zb) {
        if (zb == 1) {
            // forbid hoisting batch-1 loads above batch-0 compute (register cap)
            __builtin_amdgcn_sched_barrier(0);
        }
        // ---- loads for z-planes {2*zb, 2*zb+1} (scalar-skipped) ----
#pragma unroll
        for (int dz = 0; dz < 2; ++dz) {
            const int iz = 2 * zb + dz;
            if (zw[iz] == 0) continue;
#pragma unroll
            for (int iy = 0; iy < 4; ++iy) {
                if (yw[iy] == 0) continue;
                q[dz * 4 + iy] = *(const uint4*)(lanep + zrow[iz] + yoff[iy]);
            }
        }
        // ---- packed FMA over the same nonzero rows ----
#pragma unroll
        for (int dz = 0; dz < 2; ++dz) {
            const int iz = 2 * zb + dz;
            if (zw[iz] == 0) continue;
#pragma unroll
            for (int iy = 0; iy < 4; ++iy) {
                if (yw[iy] == 0) continue;
                const float wf = (az.w[iz] * ay.w[iy]) * wxl;
                f32x2 wf2; wf2.x = wf; wf2.y = wf;
                const uint4 qq = q[dz * 4 + iy];
                f32x2 p;
                p.x = __uint_as_float(qq.x << 16);
                p.y = __uint_as_float(qq.x & 0xffff0000u);
                acc2[0] = __builtin_elementwise_fma(p, wf2, acc2[0]);
                p.x = __uint_as_float(qq.y << 16);
                p.y = __uint_as_float(qq.y & 0xffff0000u);
                acc2[1] = __builtin_elementwise_fma(p, wf2, acc2[1]);
                p.x = __uint_as_float(qq.z << 16);
                p.y = __uint_as_float(qq.z & 0xffff0000u);
                acc2[2] = __builtin_elementwise_fma(p, wf2, acc2[2]);
                p.x = __uint_as_float(qq.w << 16);
                p.y = __uint_as_float(qq.w & 0xffff0000u);
                acc2[3] = __builtin_elementwise_fma(p, wf2, acc2[3]);
            }
        }
    }

    // reduce over the 4 x-voxel partitions (lanes ^16, ^32)
#pragma unroll
    for (int j = 0; j < 4; ++j) {
        float sx = acc2[j].x;
        sx += __shfl_xor(sx, 16);
        sx += __shfl_xor(sx, 32);
        float sy = acc2[j].y;
        sy += __shfl_xor(sy, 16);
        sy += __shfl_xor(sy, 32);
        if (lane < 16) {
            tile[w][lane * 8 + 2 * j]     = sx;
            tile[w][lane * 8 + 2 * j + 1] = sy;
        }
    }

    __syncthreads();

    // Store: out[roi][c][pd*49 + part*7 + o], o in 0..6 contiguous per channel.
    const size_t obase =
        (size_t)roi * C_ * BINS_PER_ROI + (size_t)pd * SLAB + (size_t)part * 7;
#pragma unroll
    for (int it = 0; it < 2; ++it) {
        const int idx = t + it * 448; // 0..895 = 128 ch * 7 slots
        const int c = idx / 7;
        const int o = idx - c * 7;
        __builtin_nontemporal_store(tile[o][c],
                                    &out[obase + (size_t)c * BINS_PER_ROI + o]);
    }
}

// ---------------------------------------------------------------------------
// Fallback: thread-per-output, native layout (tiny ws only).
// ---------------------------------------------------------------------------
__global__ void roi_align_direct(const float* __restrict__ feat,
                                 const float* __restrict__ rois,
                                 float* __restrict__ out, int total) {
    const int tid = blockIdx.x * blockDim.x + threadIdx.x;
    if (tid >= total) return;
    int t = tid;
    const int pw = t % PW; t /= PW;
    const int ph = t % PH; t /= PH;
    const int pd = t % PD; t /= PD;
    const int c = t % C_;  t /= C_;
    const int r = t;

    const float* roi = rois + (size_t)r * 7;
    const int b = (int)roi[0];
    const float x1 = roi[1] * SCALE, y1 = roi[2] * SCALE, z1 = roi[3] * SCALE;
    const float x2 = roi[4] * SCALE, y2 = roi[5] * SCALE, z2 = roi[6] * SCALE;
    const float rd = fmaxf(z2 - z1, 1.0f);
    const float rh = fmaxf(y2 - y1, 1.0f);
    const float rw = fmaxf(x2 - x1, 1.0f);

    int zlo[2], zhi[2], ylo[2], yhi[2], xlo[2], xhi[2];
    float wz[2], wy[2], wx[2];
    bool vz[2], vy[2], vx[2];
    axis2(z1, rd, PD, pd, D_, zlo, zhi, wz, vz);
    axis2(y1, rh, PH, ph, H_, ylo, yhi, wy, vy);
    axis2(x1, rw, PW, pw, W_, xlo, xhi, wx, vx);

    const float* fc = feat + ((size_t)b * C_ + c) * S_;
    float acc = 0.0f;
#pragma unroll
    for (int i = 0; i < 2; ++i) {
        if (!vz[i]) continue;
#pragma unroll
        for (int j = 0; j < 2; ++j) {
            if (!vy[j]) continue;
            const size_t r00 = ((size_t)zlo[i] * H_ + ylo[j]) * W_;
            const size_t r10 = ((size_t)zhi[i] * H_ + ylo[j]) * W_;
            const size_t r01 = ((size_t)zlo[i] * H_ + yhi[j]) * W_;
            const size_t r11 = ((size_t)zhi[i] * H_ + yhi[j]) * W_;
            const float wz1 = wz[i], wz0 = 1.0f - wz1;
            const float wy1 = wy[j], wy0 = 1.0f - wy1;
#pragma unroll
            for (int k = 0; k < 2; ++k) {
                if (!vx[k]) continue;
                const float wx1 = wx[k], wx0 = 1.0f - wx1;
                acc += wz0 * (wy0 * (wx0 * fc[r00 + xlo[k]] + wx1 * fc[r00 + xhi[k]]) +
                              wy1 * (wx0 * fc[r01 + xlo[k]] + wx1 * fc[r01 + xhi[k]])) +
                       wz1 * (wy0 * (wx0 * fc[r10 + xlo[k]] + wx1 * fc[r10 + xhi[k]]) +
                              wy1 * (wx0 * fc[r11 + xlo[k]] + wx1 * fc[r11 + xhi[k]]));
            }
        }
    }
    out[tid] = acc * (1.0f / (SR * SR * SR));
}

extern "C" void kernel_launch(void* const* d_in, const int* in_sizes, int n_in,
                              void* d_out, int out_size, void* d_ws,
                              size_t ws_size, hipStream_t stream) {
    const float* features = (const float*)d_in[0];
    const float* rois = (const float*)d_in[1];
    float* out = (float*)d_out;

    const int R = in_sizes[1] / 7;
    const int N = in_sizes[0] / (C_ * S_);
    const size_t need = (size_t)in_sizes[0] * sizeof(unsigned short) + 1024;

    if (ws_size >= need) {
        unsigned short* ft = (unsigned short*)d_ws; // [N, D, H, W, C] bf16

        dim3 tg(S_ / 256, N);
        transpose_bf16<<<tg, 512, 0, stream>>>(features, (unsigned int*)ft);

        roi_align_slot<<<R * PD * 7, 448, 0, stream>>>(ft, rois, out, R);
    } else {
        const int total = R * C_ * BINS_PER_ROI;
        roi_align_direct<<<(total + 255) / 256, 256, 0, stream>>>(
            features, rois, out, total);
    }
}